// Round 10
// baseline (376.459 us; speedup 1.0000x reference)
//
#include <hip/hip_runtime.h>
#include <hip/hip_bf16.h>
#include <stdint.h>

#define N_NODES 50000
#define N_EDGES 800000
#define IN_DIM 64
#define HID 128
#define OUT_DIM 64
#define T_HIST 8

#define NB_SCAN ((N_NODES + 1023) / 1024)   // 49 scan blocks, 1024 nodes each

typedef __attribute__((ext_vector_type(8))) short short8;
typedef __attribute__((ext_vector_type(4))) float f32x4;

__device__ __forceinline__ unsigned short f2bf(float x) {
  unsigned int u = __builtin_bit_cast(unsigned int, x);
  unsigned int r = (u + 0x7FFFu + ((u >> 16) & 1u)) >> 16;
  return (unsigned short)r;
}
__device__ __forceinline__ short8 cvt8(float4 a, float4 b) {
  unsigned int w0, w1, w2, w3;
  asm("v_cvt_pk_bf16_f32 %0, %1, %2" : "=v"(w0) : "v"(a.x), "v"(a.y));
  asm("v_cvt_pk_bf16_f32 %0, %1, %2" : "=v"(w1) : "v"(a.z), "v"(a.w));
  asm("v_cvt_pk_bf16_f32 %0, %1, %2" : "=v"(w2) : "v"(b.x), "v"(b.y));
  asm("v_cvt_pk_bf16_f32 %0, %1, %2" : "=v"(w3) : "v"(b.z), "v"(b.w));
  struct { unsigned int a, b, c, d; } s{w0, w1, w2, w3};
  return __builtin_bit_cast(short8, s);
}
// sigmoid/tanh via exp2+rcp; safe at +-inf
__device__ __forceinline__ float sigm(float x) {
  float e = __builtin_amdgcn_exp2f(-1.4426950408889634f * x);
  return __builtin_amdgcn_rcpf(1.f + e);
}
__device__ __forceinline__ float tanh_f(float x) {
  float e = __builtin_amdgcn_exp2f(2.8853900817779268f * x);
  return 1.f - 2.f * __builtin_amdgcn_rcpf(e + 1.f);
}

// ---------------- prepack + count (independent work, fused; cnt pre-zeroed by memset) ----------------
// Wt2:   LSTM weights, frag order F = q*32 + g*8 + kk (k=256)
// Wc2:   W_cls [128][64], frag order F = cb*4 + kk (k=128)
// Wsnc2: folded SAGE->cls weights S [128][64]: rows 0..63 = W_self@W_cls, 64..127 = W_neigh@W_cls
// bc1:   b_sage@W_cls + b_cls
__global__ void pc_kernel(const float* __restrict__ w_ih, const float* __restrict__ w_hh,
                          const float* __restrict__ W_cls,
                          const float* __restrict__ W_self, const float* __restrict__ W_neigh,
                          const float* __restrict__ b_sage, const float* __restrict__ b_cls,
                          const int* __restrict__ dst,
                          unsigned short* __restrict__ Wt2, unsigned short* __restrict__ Wc2,
                          unsigned short* __restrict__ Wsnc2,
                          float* __restrict__ bc1, int* __restrict__ cnt) {
  int tid = blockIdx.x * blockDim.x + threadIdx.x;
  int stride = gridDim.x * blockDim.x;
  // count (largest share first)
  for (int e = tid; e < N_EDGES; e += stride) atomicAdd(&cnt[dst[e]], 1);
  // Wt2 fragments
  for (int idx = tid; idx < 256 * 512; idx += stride) {
    int i = idx & 7;
    int lane = (idx >> 3) & 63;
    int F = idx >> 9;
    int q = F >> 5, g = (F >> 3) & 3, kk = F & 7;
    int c = g * 128 + q * 16 + (lane & 15);
    int k = kk * 32 + (lane >> 4) * 8 + i;
    float v = (k < 128) ? w_ih[k * 512 + c] : w_hh[(k - 128) * 512 + c];
    Wt2[idx] = f2bf(v);
  }
  // Wc2 fragments
  for (int idx = tid; idx < 16 * 512; idx += stride) {
    int i = idx & 7;
    int lane = (idx >> 3) & 63;
    int F = idx >> 9;
    int cb = F >> 2, kk = F & 3;
    int col = cb * 16 + (lane & 15);
    int k = kk * 32 + (lane >> 4) * 8 + i;
    Wc2[idx] = f2bf(W_cls[k * 64 + col]);
  }
  // Wsnc2 fragments (folded SAGE-classifier weights, computed on the fly)
  for (int idx = tid; idx < 16 * 512; idx += stride) {
    int i = idx & 7;
    int lane = (idx >> 3) & 63;
    int F = idx >> 9;
    int cb = F >> 2, kk = F & 3;
    int col = cb * 16 + (lane & 15);
    int k = kk * 32 + (lane >> 4) * 8 + i;   // 0..127
    const float* Wrow = (k < 64) ? &W_self[k * 128] : &W_neigh[(k - 64) * 128];
    float v = 0.f;
    for (int m = 0; m < 128; m++) v += Wrow[m] * W_cls[m * 64 + col];
    Wsnc2[idx] = f2bf(v);
  }
  for (int c = tid; c < 64; c += stride) {
    float acc = b_cls[c];
    for (int m = 0; m < 128; m++) acc += b_sage[m] * W_cls[m * 64 + c];
    bc1[c] = acc;
  }
}

// ---------------- scan1: block-local exclusive scan (1024 nodes/block) ----------------
__global__ __launch_bounds__(256) void scan1_kernel(const int* __restrict__ cnt,
                                                    int* __restrict__ lexcl, int* __restrict__ btot) {
  __shared__ int sh[256];
  int tid = threadIdx.x;
  int base = blockIdx.x * 1024 + tid * 4;
  int v[4];
  #pragma unroll
  for (int q = 0; q < 4; q++) {
    int i = base + q;
    v[q] = (i < N_NODES) ? cnt[i] : 0;
  }
  int tsum = v[0] + v[1] + v[2] + v[3];
  sh[tid] = tsum;
  __syncthreads();
  int val = tsum;
  for (int off = 1; off < 256; off <<= 1) {
    int x = (tid >= off) ? sh[tid - off] : 0;
    __syncthreads();
    val += x;
    sh[tid] = val;
    __syncthreads();
  }
  int ex = val - tsum;  // exclusive
  if (tid == 255) btot[blockIdx.x] = val;
  #pragma unroll
  for (int q = 0; q < 4; q++) {
    int i = base + q;
    if (i < N_NODES) lexcl[i] = ex;
    ex += v[q];
  }
}

// ---------------- scan3: rowstart/cursor = lexcl + prefix(btot) ----------------
__global__ __launch_bounds__(1024) void scan3_kernel(const int* __restrict__ lexcl,
                                                     const int* __restrict__ btot,
                                                     int* __restrict__ rowstart, int* __restrict__ cursor) {
  int b = blockIdx.x;
  int bs = 0;
  for (int j = 0; j < b; j++) bs += btot[j];   // <=48 L2-hit loads
  int i = b * 1024 + threadIdx.x;
  if (i < N_NODES) {
    int rs = lexcl[i] + bs;
    rowstart[i] = rs;
    cursor[i] = rs;
  }
}

// ---------------- fill ----------------
__global__ void fill_kernel(const int* __restrict__ src, const int* __restrict__ dst,
                            int* __restrict__ cursor, int* __restrict__ esrc) {
  int e = blockIdx.x * blockDim.x + threadIdx.x;
  if (e < N_EDGES) {
    int d = dst[e];
    int pos = atomicAdd(&cursor[d], 1);
    esrc[pos] = src[e];
  }
}

// ---------------- fused LSTM (8 steps) + SAGE gather + full classifier ----------------
// Core = R6/R9-proven structure: 512 thr = 8 waves, 64 nodes/block, wave owns
// 16 cols x 4 gates, 4 row-block passes, double-buffered A, 1 barrier/step.
// Epilogue: out = h_temp@W_cls + [nf|hn]@Wsnc + bc1, all via MFMA into one acc.
#define LB 64
__global__ __launch_bounds__(512, 2) void lstm_kernel(
    const float* __restrict__ hist,          // [N][8][128] f32
    const unsigned short* __restrict__ Wt2,  // frag-ordered bf16
    const unsigned short* __restrict__ Wc2,  // frag-ordered bf16 (k=128)
    const unsigned short* __restrict__ Wsnc2,// frag-ordered bf16 (k=128, folded SAGE)
    const float* __restrict__ b_lstm,        // [512]
    const float* __restrict__ nf,            // [N][64]
    const int* __restrict__ esrc,            // CSR neighbor sources
    const int* __restrict__ rowstart,        // [N]
    const int* __restrict__ cnt,             // [N] degrees
    const float* __restrict__ bc1,           // [64]
    float* __restrict__ out)                 // [N][64]
{
  __shared__ alignas(16) unsigned short Abuf[2][64 * 256];  // 2 x 32KB, [row][swz(kb)][8]

  const int tid = threadIdx.x;
  const int lane = tid & 63;
  const int w = tid >> 6;
  const int l15 = lane & 15;
  const int l4 = lane >> 4;
  const int base = blockIdx.x * LB;
  const int jj = w * 16 + l15;     // hidden unit owned by this lane

  // persistent B fragments: Bfr[g][kk]  (128 VGPR)
  short8 Bfr[4][8];
  #pragma unroll
  for (int g = 0; g < 4; g++)
    #pragma unroll
    for (int kk = 0; kk < 8; kk++)
      Bfr[g][kk] = *(const short8*)&Wt2[((w * 32 + g * 8 + kk) * 64 + lane) * 8];

  const float bi  = b_lstm[jj];
  const float bf_ = b_lstm[128 + jj];
  const float bg  = b_lstm[256 + jj];
  const float bo  = b_lstm[384 + jj];

  float c_st[16];
  #pragma unroll
  for (int i = 0; i < 16; i++) c_st[i] = 0.f;

  // prologue: zero h-region of buf0, stage x(0) into buf0
  for (int u = tid; u < 64 * 16; u += 512) {
    int row = u >> 4;
    int kbh = u & 15;
    short8 z = {0,0,0,0,0,0,0,0};
    *(short8*)&Abuf[0][row * 256 + 128 + kbh * 8] = z;
  }
  #pragma unroll
  for (int i2 = 0; i2 < 2; i2++) {
    int u = tid + (i2 << 9);
    int row = u >> 4;
    int kb = u & 15;
    int node = base + row;
    float4 x0 = make_float4(0.f,0.f,0.f,0.f), x1 = make_float4(0.f,0.f,0.f,0.f);
    if (node < N_NODES) {
      const float4* p = (const float4*)&hist[(size_t)node * (T_HIST * HID) + kb * 8];
      x0 = p[0]; x1 = p[1];
    }
    int sb = (kb & 8) | ((kb & 7) ^ (row & 7));
    *(short8*)&Abuf[0][row * 256 + sb * 8] = cvt8(x0, x1);
  }
  __syncthreads();

  float4 xp[4];  // prefetch regs (16 VGPR)

  // ---- steps 0..6 ----
  #pragma unroll
  for (int t = 0; t < T_HIST - 1; t++) {
    unsigned short* Acur = &Abuf[t & 1][0];
    unsigned short* Anxt = &Abuf[(t & 1) ^ 1][0];

    // issue x(t+1) global loads early: latency hides under MFMA phase
    #pragma unroll
    for (int i2 = 0; i2 < 2; i2++) {
      int u = tid + (i2 << 9);
      int row = u >> 4;
      int kb = u & 15;
      int node = base + row;
      if (node < N_NODES) {
        const float4* p = (const float4*)&hist[(size_t)node * (T_HIST * HID) + (t + 1) * HID + kb * 8];
        xp[i2 * 2]     = p[0];
        xp[i2 * 2 + 1] = p[1];
      } else {
        xp[i2 * 2]     = make_float4(0.f,0.f,0.f,0.f);
        xp[i2 * 2 + 1] = make_float4(0.f,0.f,0.f,0.f);
      }
    }

    // 4 row-block passes; acc (16 VGPR) dies at end of each pass
    #pragma unroll
    for (int rb = 0; rb < 4; rb++) {
      f32x4 acc[4];
      #pragma unroll
      for (int g = 0; g < 4; g++) { f32x4 z = {0.f,0.f,0.f,0.f}; acc[g] = z; }
      #pragma unroll
      for (int kk = 0; kk < 8; kk++) {
        int row = rb * 16 + l15;
        int kb = kk * 4 + l4;
        int sb = (kb & 24) | ((kb & 7) ^ (row & 7));
        short8 a = *(const short8*)&Acur[row * 256 + sb * 8];
        #pragma unroll
        for (int g = 0; g < 4; g++)
          acc[g] = __builtin_amdgcn_mfma_f32_16x16x32_bf16(a, Bfr[g][kk], acc[g], 0, 0, 0);
      }
      // cell update for this row block; h -> Anxt h-region
      #pragma unroll
      for (int reg = 0; reg < 4; reg++) {
        int r = rb * 4 + reg;
        float gi = sigm(acc[0][reg] + bi);
        float gf = sigm(acc[1][reg] + bf_);
        float gg = tanh_f(acc[2][reg] + bg);
        float go = sigm(acc[3][reg] + bo);
        float c = gf * c_st[r] + gi * gg;
        c_st[r] = c;
        float h = go * tanh_f(c);
        int row = rb * 16 + l4 * 4 + reg;
        int kb = 16 + (jj >> 3);
        int sb = (kb & 24) | ((kb & 7) ^ (row & 7));
        Anxt[row * 256 + sb * 8 + (jj & 7)] = f2bf(h);
      }
      __builtin_amdgcn_sched_barrier(0);  // keep passes separate: acc stays 16 regs
    }

    // write staged x(t+1) into next buffer's x-region
    #pragma unroll
    for (int i2 = 0; i2 < 2; i2++) {
      int u = tid + (i2 << 9);
      int row = u >> 4;
      int kb = u & 15;
      int sb = (kb & 8) | ((kb & 7) ^ (row & 7));
      *(short8*)&Anxt[row * 256 + sb * 8] = cvt8(xp[i2 * 2], xp[i2 * 2 + 1]);
    }
    __syncthreads();   // single barrier per step
  }

  // ---- t = 7 (peeled): final step; h_temp -> Abuf[0] x-region ----
  {
    unsigned short* Acur = &Abuf[1][0];
    unsigned short* Anxt = &Abuf[0][0];

    #pragma unroll
    for (int rb = 0; rb < 4; rb++) {
      f32x4 acc[4];
      #pragma unroll
      for (int g = 0; g < 4; g++) { f32x4 z = {0.f,0.f,0.f,0.f}; acc[g] = z; }
      #pragma unroll
      for (int kk = 0; kk < 8; kk++) {
        int row = rb * 16 + l15;
        int kb = kk * 4 + l4;
        int sb = (kb & 24) | ((kb & 7) ^ (row & 7));
        short8 a = *(const short8*)&Acur[row * 256 + sb * 8];
        #pragma unroll
        for (int g = 0; g < 4; g++)
          acc[g] = __builtin_amdgcn_mfma_f32_16x16x32_bf16(a, Bfr[g][kk], acc[g], 0, 0, 0);
      }
      #pragma unroll
      for (int reg = 0; reg < 4; reg++) {
        int r = rb * 4 + reg;
        float gi = sigm(acc[0][reg] + bi);
        float gf = sigm(acc[1][reg] + bf_);
        float gg = tanh_f(acc[2][reg] + bg);
        float go = sigm(acc[3][reg] + bo);
        float c = gf * c_st[r] + gi * gg;
        float h = go * tanh_f(c);
        int row = rb * 16 + l4 * 4 + reg;
        int kb = jj >> 3;
        int sb = (kb & 8) | ((kb & 7) ^ (row & 7));
        Anxt[row * 256 + sb * 8 + (jj & 7)] = f2bf(h);
      }
      __builtin_amdgcn_sched_barrier(0);
    }

    // ---- SAGE gather: nf + mean-neighbor rows into registers ----
    // (overlaps other waves' t=7 MFMA; Abuf[0] h-region is dead, write directly)
    float nfreg[8], hnreg[8];
    #pragma unroll
    for (int rr = 0; rr < 8; rr++) {
      int node = base + w * 8 + rr;
      nfreg[rr] = (node < N_NODES) ? nf[node * 64 + lane] : 0.f;
    }
    for (int rr = 0; rr < 8; rr++) {
      int node = base + w * 8 + rr;
      float a0 = 0.f, a1 = 0.f, a2 = 0.f, a3 = 0.f;
      int n = 0;
      if (node < N_NODES) {
        n = cnt[node];
        int st = rowstart[node];
        int j = 0;
        for (; j + 4 <= n; j += 4) {
          int s0 = esrc[st + j], s1 = esrc[st + j + 1];
          int s2 = esrc[st + j + 2], s3 = esrc[st + j + 3];
          a0 += nf[s0 * 64 + lane];
          a1 += nf[s1 * 64 + lane];
          a2 += nf[s2 * 64 + lane];
          a3 += nf[s3 * 64 + lane];
        }
        for (; j < n; j++) a0 += nf[esrc[st + j] * 64 + lane];
      }
      hnreg[rr] = (a0 + a1 + a2 + a3) * __builtin_amdgcn_rcpf(fmaxf((float)n, 1.f));
    }
    // write [nf|hn] into Abuf[0] h-region: nf -> kb 16..23, hn -> kb 24..31
    #pragma unroll
    for (int rr = 0; rr < 8; rr++) {
      int row = w * 8 + rr;
      int kbn = 16 + (lane >> 3);
      int sbn = (kbn & 24) | ((kbn & 7) ^ (row & 7));
      Anxt[row * 256 + sbn * 8 + (lane & 7)] = f2bf(nfreg[rr]);
      int kbh = 24 + (lane >> 3);
      int sbh = (kbh & 24) | ((kbh & 7) ^ (row & 7));
      Anxt[row * 256 + sbh * 8 + (lane & 7)] = f2bf(hnreg[rr]);
    }
    __syncthreads();

    // ---- classifier + SAGE: out = h_temp@W_cls + [nf|hn]@Wsnc + bc1 ----
    #pragma unroll
    for (int fi = 0; fi < 2; fi++) {
      int f = w * 2 + fi;
      int rbo = f >> 2, cbo = f & 3;
      int col = cbo * 16 + l15;
      f32x4 o = {0.f, 0.f, 0.f, 0.f};
      #pragma unroll
      for (int kk = 0; kk < 4; kk++) {
        short8 bv = *(const short8*)&Wc2[((cbo * 4 + kk) * 64 + lane) * 8];
        int row = rbo * 16 + l15;
        int kb = kk * 4 + l4;
        int sb = (kb & 8) | ((kb & 7) ^ (row & 7));
        short8 a = *(const short8*)&Anxt[row * 256 + sb * 8];
        o = __builtin_amdgcn_mfma_f32_16x16x32_bf16(a, bv, o, 0, 0, 0);
      }
      #pragma unroll
      for (int kk = 0; kk < 4; kk++) {
        short8 bv = *(const short8*)&Wsnc2[((cbo * 4 + kk) * 64 + lane) * 8];
        int row = rbo * 16 + l15;
        int kb = 16 + kk * 4 + l4;
        int sb = (kb & 24) | ((kb & 7) ^ (row & 7));
        short8 a = *(const short8*)&Anxt[row * 256 + sb * 8];
        o = __builtin_amdgcn_mfma_f32_16x16x32_bf16(a, bv, o, 0, 0, 0);
      }
      float bcl = bc1[col];
      #pragma unroll
      for (int reg = 0; reg < 4; reg++) {
        int row = rbo * 16 + l4 * 4 + reg;
        int node = base + row;
        if (node < N_NODES) out[(size_t)node * OUT_DIM + col] = o[reg] + bcl;
      }
    }
  }
}

// ---------------- launch ----------------
extern "C" void kernel_launch(void* const* d_in, const int* in_sizes, int n_in,
                              void* d_out, int out_size, void* d_ws, size_t ws_size,
                              hipStream_t stream) {
  (void)in_sizes; (void)n_in; (void)out_size; (void)ws_size;
  const float* node_feats = (const float*)d_in[0];
  const float* hist       = (const float*)d_in[1];
  const int*   src        = (const int*)d_in[2];
  const int*   dst        = (const int*)d_in[3];
  const float* W_self     = (const float*)d_in[4];
  const float* W_neigh    = (const float*)d_in[5];
  const float* b_sage     = (const float*)d_in[6];
  const float* w_ih       = (const float*)d_in[7];
  const float* w_hh       = (const float*)d_in[8];
  const float* b_lstm     = (const float*)d_in[9];
  const float* W_cls      = (const float*)d_in[10];
  const float* b_cls      = (const float*)d_in[11];
  float* out = (float*)d_out;

  char* ws = (char*)d_ws;
  int* cnt        = (int*)(ws);                        // 200,192
  int* lexcl      = (int*)(ws + 200192);               // -> 400,384
  int* rowstart   = (int*)(ws + 400384);               // -> 600,576
  int* cursor     = (int*)(ws + 600576);               // -> 800,768
  int* btot       = (int*)(ws + 800768);               // -> 801,792
  int* esrc       = (int*)(ws + 801792);               // -> 4,001,792
  unsigned short* Wt2   = (unsigned short*)(ws + 4001792);  // -> 4,263,936
  unsigned short* Wc2   = (unsigned short*)(ws + 4263936);  // -> 4,280,320
  unsigned short* Wsnc2 = (unsigned short*)(ws + 4280320);  // -> 4,296,704
  float* bc1      = (float*)(ws + 4296704);            // -> 4,296,960

  hipMemsetAsync(cnt, 0, 200000, stream);
  pc_kernel<<<1024, 256, 0, stream>>>(w_ih, w_hh, W_cls, W_self, W_neigh, b_sage, b_cls,
                                      dst, Wt2, Wc2, Wsnc2, bc1, cnt);
  scan1_kernel<<<NB_SCAN, 256, 0, stream>>>(cnt, lexcl, btot);
  scan3_kernel<<<NB_SCAN, 1024, 0, stream>>>(lexcl, btot, rowstart, cursor);
  fill_kernel<<<(N_EDGES + 255) / 256, 256, 0, stream>>>(src, dst, cursor, esrc);
  lstm_kernel<<<(N_NODES + LB - 1) / LB, 512, 0, stream>>>(
      hist, Wt2, Wc2, Wsnc2, b_lstm, node_feats, esrc, rowstart, cnt, bc1, out);
}